// Round 3
// baseline (110.500 us; speedup 1.0000x reference)
//
#include <hip/hip_runtime.h>

#define IMG_H 256
#define IMG_W 256
#define TW 64
#define TH 16
#define HR 22     // TH + 6 halo rows
#define HSTR 65   // padded LDS row length (float4 units): row stride 260 dwords -> bank-uniform

// Gaussian 7-tap, f64-derived f32 constants (matches numpy f32 recipe to ~1e-7 rel)
#define G0 0.03663285f
#define G1 0.11128076f
#define G2 0.21674532f
#define G3 0.27068216f

// Fused SSIM, horizontal-first:
//  phase 1: 176 tasks (22 halo rows x 8 groups) compute 8 h-filtered outputs each
//           directly from global (4 aligned float4 loads per image), write
//           (sx,sy,sxx,syy) as float4 + sxy scalar to LDS.
//  phase 2: lane=column vertical 7-tap (10 shared taps -> 4 rows/thread),
//           SSIM map, block reduction.
__global__ __launch_bounds__(256) void ssim_tile_kernel(
    const float* __restrict__ x, const float* __restrict__ y,
    float* __restrict__ partial) {
    __shared__ float4 hA[HR][HSTR];   // sx, sy, sxx, syy
    __shared__ float  hB[HR][HSTR];   // sxy
    __shared__ float  wsum[4];

    const int tid = threadIdx.x;
    const int bx = blockIdx.x, by = blockIdx.y, plane = blockIdx.z;
    const int r0 = by * TH;
    const int c0 = bx * TW;
    const size_t base = (size_t)plane * (IMG_H * IMG_W);

    const float g[7] = {G0, G1, G2, G3, G2, G1, G0};

    // ---------------- Phase 1: horizontal pass ----------------
    if (tid < HR * 8) {
        const int rr = tid >> 3;          // halo row 0..21
        const int k  = tid & 7;           // col group -> outputs 8k..8k+7
        const int gr = r0 - 3 + rr;       // global row
        const int gc0 = c0 + 8 * k - 3;   // first input col (14 inputs gc0..gc0+13)

        float xin[16], yin[16];
        const bool row_ok = ((unsigned)gr < IMG_H);
        const bool col_interior = (bx > 0) & (bx < 3);

        if (row_ok & col_interior) {
            // (gc0-1) % 4 == 0: 4 aligned float4 loads cover inputs at idx 1..14
            const float4* p4 = (const float4*)(x + base + (size_t)gr * IMG_W + (gc0 - 1));
            const float4* q4 = (const float4*)(y + base + (size_t)gr * IMG_W + (gc0 - 1));
            float4 a0 = p4[0], a1 = p4[1], a2 = p4[2], a3 = p4[3];
            float4 b0 = q4[0], b1 = q4[1], b2 = q4[2], b3 = q4[3];
            xin[0]=a0.x; xin[1]=a0.y; xin[2]=a0.z; xin[3]=a0.w;
            xin[4]=a1.x; xin[5]=a1.y; xin[6]=a1.z; xin[7]=a1.w;
            xin[8]=a2.x; xin[9]=a2.y; xin[10]=a2.z; xin[11]=a2.w;
            xin[12]=a3.x; xin[13]=a3.y; xin[14]=a3.z; xin[15]=a3.w;
            yin[0]=b0.x; yin[1]=b0.y; yin[2]=b0.z; yin[3]=b0.w;
            yin[4]=b1.x; yin[5]=b1.y; yin[6]=b1.z; yin[7]=b1.w;
            yin[8]=b2.x; yin[9]=b2.y; yin[10]=b2.z; yin[11]=b2.w;
            yin[12]=b3.x; yin[13]=b3.y; yin[14]=b3.z; yin[15]=b3.w;
        } else if (row_ok) {
            // column-edge tiles: scalar loads with clamp + zero-mask
            const float* prow = x + base + (size_t)gr * IMG_W;
            const float* qrow = y + base + (size_t)gr * IMG_W;
            xin[0] = 0.f; yin[0] = 0.f; xin[15] = 0.f; yin[15] = 0.f;
            #pragma unroll
            for (int j = 0; j < 14; ++j) {
                int gc = gc0 + j;
                bool ok = ((unsigned)gc < IMG_W);
                int gcc = gc < 0 ? 0 : (gc > IMG_W - 1 ? IMG_W - 1 : gc);
                float xv = prow[gcc];
                float yv = qrow[gcc];
                xin[j + 1] = ok ? xv : 0.f;
                yin[j + 1] = ok ? yv : 0.f;
            }
        } else {
            #pragma unroll
            for (int j = 0; j < 16; ++j) { xin[j] = 0.f; yin[j] = 0.f; }
        }

        float aX[8], aY[8], aXX[8], aYY[8], aXY[8];
        #pragma unroll
        for (int o = 0; o < 8; ++o) {
            aX[o] = 0.f; aY[o] = 0.f; aXX[o] = 0.f; aYY[o] = 0.f; aXY[o] = 0.f;
        }
        #pragma unroll
        for (int d = 0; d < 14; ++d) {
            float xv = xin[d + 1], yv = yin[d + 1];
            float xx = xv * xv, yy = yv * yv, xy = xv * yv;
            #pragma unroll
            for (int o = 0; o < 8; ++o) {
                const int t = d - o;
                if (t >= 0 && t < 7) {
                    const float gw = g[t];
                    aX[o]  = fmaf(gw, xv, aX[o]);
                    aY[o]  = fmaf(gw, yv, aY[o]);
                    aXX[o] = fmaf(gw, xx, aXX[o]);
                    aYY[o] = fmaf(gw, yy, aYY[o]);
                    aXY[o] = fmaf(gw, xy, aXY[o]);
                }
            }
        }
        #pragma unroll
        for (int o = 0; o < 8; ++o) {
            const int c = 8 * k + o;
            hA[rr][c] = make_float4(aX[o], aY[o], aXX[o], aYY[o]);
            hB[rr][c] = aXY[o];
        }
    }
    __syncthreads();

    // ---------------- Phase 2: vertical pass + SSIM ----------------
    const int c  = tid & 63;
    const int rb = (tid >> 6) * 4;   // output rows rb..rb+3

    float4 wa[10];
    float  wb[10];
    #pragma unroll
    for (int d = 0; d < 10; ++d) {
        wa[d] = hA[rb + d][c];
        wb[d] = hB[rb + d][c];
    }

    const float c1 = 0.01f * 0.01f;
    const float c2 = 0.03f * 0.03f;
    float acc = 0.f;
    #pragma unroll
    for (int o = 0; o < 4; ++o) {
        float sx = 0.f, sy = 0.f, sxx = 0.f, syy = 0.f, sxy = 0.f;
        #pragma unroll
        for (int d = 0; d < 7; ++d) {
            const float gw = g[d];
            float4 w = wa[o + d];
            sx  = fmaf(gw, w.x, sx);
            sy  = fmaf(gw, w.y, sy);
            sxx = fmaf(gw, w.z, sxx);
            syy = fmaf(gw, w.w, syy);
            sxy = fmaf(gw, wb[o + d], sxy);
        }
        float mu1s = sx * sx;
        float mu2s = sy * sy;
        float mu12 = sx * sy;
        float s1   = sxx - mu1s;
        float s2   = syy - mu2s;
        float s12  = sxy - mu12;
        float num  = fmaf(2.f, mu12, c1) * fmaf(2.f, s12, c2);
        float den  = (mu1s + mu2s + c1) * (s1 + s2 + c2);
        float rcp  = __builtin_amdgcn_rcpf(den);
        rcp = rcp * (2.f - den * rcp);   // 1 Newton step (rel err ~1e-7)
        acc = fmaf(num, rcp, acc);
    }

    // ---------------- Block reduction ----------------
    #pragma unroll
    for (int off = 32; off > 0; off >>= 1)
        acc += __shfl_down(acc, off, 64);

    const int wave = tid >> 6;
    const int lane = tid & 63;
    if (lane == 0) wsum[wave] = acc;
    __syncthreads();
    if (tid == 0) {
        float t = wsum[0] + wsum[1] + wsum[2] + wsum[3];
        partial[((size_t)blockIdx.z * 64) + blockIdx.y * 4 + blockIdx.x] = t;
    }
}

// Deterministic final reduction: single block, 1024 threads, double accumulation.
__global__ __launch_bounds__(1024) void ssim_reduce_kernel(
    const float4* __restrict__ p, float* __restrict__ out,
    int n4, double inv_count) {
    double a = 0.0;
    for (int i = threadIdx.x; i < n4; i += 1024) {
        float4 v = p[i];
        a += (double)v.x + (double)v.y + (double)v.z + (double)v.w;
    }
    #pragma unroll
    for (int off = 32; off > 0; off >>= 1)
        a += __shfl_down(a, off, 64);
    __shared__ double sd[16];
    const int wave = threadIdx.x >> 6;
    const int lane = threadIdx.x & 63;
    if (lane == 0) sd[wave] = a;
    __syncthreads();
    if (threadIdx.x == 0) {
        double t = 0.0;
        #pragma unroll
        for (int w = 0; w < 16; w++) t += sd[w];
        out[0] = (float)(t * inv_count);
    }
}

extern "C" void kernel_launch(void* const* d_in, const int* in_sizes, int n_in,
                              void* d_out, int out_size, void* d_ws, size_t ws_size,
                              hipStream_t stream) {
    const float* x = (const float*)d_in[0];
    const float* y = (const float*)d_in[1];
    float* out = (float*)d_out;
    float* partial = (float*)d_ws;

    const int total = in_sizes[0];                 // 12,582,912
    const int planes = total / (IMG_H * IMG_W);    // 192
    const int tiles_r = IMG_H / TH;                // 16
    const int tiles_c = IMG_W / TW;                // 4
    const int n_partial = planes * tiles_r * tiles_c;  // 12288

    dim3 grid(tiles_c, tiles_r, planes);
    ssim_tile_kernel<<<grid, dim3(256), 0, stream>>>(x, y, partial);

    ssim_reduce_kernel<<<1, 1024, 0, stream>>>((const float4*)partial, out,
                                               n_partial / 4, 1.0 / (double)total);
}